// Round 1
// baseline (58.599 us; speedup 1.0000x reference)
//
#include <hip/hip_runtime.h>
#include <math.h>

#define IH 512
#define IW 512
#define TS 32
#define YHALO 7              // 5 (search) + 2 (patch)
#define RHALO 5              // search only
#define YD (TS + 2*YHALO)    // 46
#define RD (TS + 2*RHALO)    // 42

__global__ __launch_bounds__(256)
void nlm_kernel(const float* __restrict__ rgb,
                const float* __restrict__ sigma,
                float* __restrict__ out) {
    __shared__ float Ylds[YD][YD];
    __shared__ float Rlds[3][RD][RD];

    const int tid = threadIdx.x;
    const int tx0 = blockIdx.x * TS;
    const int ty0 = blockIdx.y * TS;

    const float* Rp = rgb;
    const float* Gp = rgb + IH * IW;
    const float* Bp = rgb + 2 * IH * IW;

    // ---- fill luminance LDS (tile + halo 7), circular wrap ----
    for (int idx = tid; idx < YD * YD; idx += 256) {
        int a = idx / YD, b = idx - a * YD;
        int gy = (ty0 + a - YHALO) & (IH - 1);
        int gx = (tx0 + b - YHALO) & (IW - 1);
        int g = gy * IW + gx;
        Ylds[a][b] = 0.299f * Rp[g] + 0.587f * Gp[g] + 0.114f * Bp[g];
    }
    // ---- fill rgb LDS (tile + halo 5), circular wrap ----
    for (int idx = tid; idx < RD * RD; idx += 256) {
        int a = idx / RD, b = idx - a * RD;
        int gy = (ty0 + a - RHALO) & (IH - 1);
        int gx = (tx0 + b - RHALO) & (IW - 1);
        int g = gy * IW + gx;
        Rlds[0][a][b] = Rp[g];
        Rlds[1][a][b] = Gp[g];
        Rlds[2][a][b] = Bp[g];
    }
    __syncthreads();

    const float hval = fmaxf(sigma[0] * 2.0f, 0.0f) + 1e-6f;
    const float inv_h = 1.0f / hval;

    const int tx = tid & 31;   // column within tile
    const int tz = tid >> 5;   // row strip 0..7; rows tz*4 .. tz*4+3

    // cache base-Y patch: rows tz*4-2 .. tz*4+5, cols tx-2 .. tx+2
    float yb[8][5];
    #pragma unroll
    for (int i = 0; i < 8; ++i)
        #pragma unroll
        for (int b = 0; b < 5; ++b)
            yb[i][b] = Ylds[YHALO + tz * 4 - 2 + i][YHALO + tx - 2 + b];

    float accR[4] = {0.f, 0.f, 0.f, 0.f};
    float accG[4] = {0.f, 0.f, 0.f, 0.f};
    float accB[4] = {0.f, 0.f, 0.f, 0.f};
    float den[4]  = {0.f, 0.f, 0.f, 0.f};

    for (int dx = -5; dx <= 5; ++dx) {
        #pragma unroll
        for (int dy = -5; dy <= 5; ++dy) {
            // horizontal patch sums for the 8 rows this strip touches
            float hs[8];
            #pragma unroll
            for (int i = 0; i < 8; ++i) {
                float s = 0.f;
                #pragma unroll
                for (int b = 0; b < 5; ++b) {
                    float ys = Ylds[YHALO + tz * 4 - 2 + i - dy]
                                   [YHALO + tx - 2 + b - dx];
                    float d = yb[i][b] - ys;
                    s = fmaf(d, d, s);
                }
                hs[i] = s;
            }
            #pragma unroll
            for (int rr = 0; rr < 4; ++rr) {
                float box = hs[rr] + hs[rr + 1] + hs[rr + 2] + hs[rr + 3] + hs[rr + 4];
                float w = __expf(-sqrtf(box) * inv_h);
                int sr = RHALO + tz * 4 + rr - dy;
                int sc = RHALO + tx - dx;
                accR[rr] = fmaf(w, Rlds[0][sr][sc], accR[rr]);
                accG[rr] = fmaf(w, Rlds[1][sr][sc], accG[rr]);
                accB[rr] = fmaf(w, Rlds[2][sr][sc], accB[rr]);
                den[rr] += w;
            }
        }
    }

    #pragma unroll
    for (int rr = 0; rr < 4; ++rr) {
        int gy = ty0 + tz * 4 + rr;
        int gx = tx0 + tx;
        int g = gy * IW + gx;
        float inv_d = 1.0f / den[rr];
        out[g]               = fminf(fmaxf(accR[rr] * inv_d, 0.f), 1.f);
        out[g + IH * IW]     = fminf(fmaxf(accG[rr] * inv_d, 0.f), 1.f);
        out[g + 2 * IH * IW] = fminf(fmaxf(accB[rr] * inv_d, 0.f), 1.f);
    }
}

extern "C" void kernel_launch(void* const* d_in, const int* in_sizes, int n_in,
                              void* d_out, int out_size, void* d_ws, size_t ws_size,
                              hipStream_t stream) {
    const float* rgb   = (const float*)d_in[0];
    const float* sigma = (const float*)d_in[1];
    float* out = (float*)d_out;

    dim3 grid(IW / TS, IH / TS);   // 16 x 16
    dim3 block(256);
    nlm_kernel<<<grid, block, 0, stream>>>(rgb, sigma, out);
}